// Round 1
// baseline (199.841 us; speedup 1.0000x reference)
//
#include <hip/hip_runtime.h>
#include <hip/hip_bf16.h>

// Problem constants (fixed by reference): B=8, T=2048, C=1024, D=64
#define TB 8
#define TT 2048
#define TC 1024
#define TD 64
#define SP 72   // LDS row stride in bf16 elems: 144B = 16B-aligned, 2-way bank alias (free)

typedef __attribute__((ext_vector_type(8))) short bf16x8;
typedef __attribute__((ext_vector_type(4))) float f32x4;

__device__ __forceinline__ short f2bf(float f) {
    union { float f; unsigned u; } v; v.f = f;
    unsigned r = v.u + 0x7fffu + ((v.u >> 16) & 1u);   // RNE
    return (short)(r >> 16);
}

// ---------------------------------------------------------------------------
// Kernel 1: fuse + transpose weights to bf16. Wt[n][k], n: 0..63=Wk, 64..127=Wq
// (pre-scaled by 0.125 = d^-0.5, exact), 128..191=Wv.  W* are [1024][64] fp32.
// ---------------------------------------------------------------------------
__global__ __launch_bounds__(256) void convert_w(const float* __restrict__ Wk,
                                                 const float* __restrict__ Wq,
                                                 const float* __restrict__ Wv,
                                                 short* __restrict__ Wt) {
    int n = blockIdx.x;                 // 0..191
    const float* src; float scale = 1.0f;
    int c = n & 63;
    if (n < 64)       { src = Wk; }
    else if (n < 128) { src = Wq; scale = 0.125f; }
    else              { src = Wv; }
    for (int kk = threadIdx.x; kk < TC; kk += 256)
        Wt[n * TC + kk] = f2bf(src[kk * TD + c] * scale);
}

// ---------------------------------------------------------------------------
// Kernel 2: QKV projection.  [16384,1024] x [1024,192] -> q,k,v bf16 [16384,64]
// Block: 64 rows x 192 cols, 4 waves (wave w = 16-row m-tile w, all 12 n-tiles)
// ---------------------------------------------------------------------------
__global__ __launch_bounds__(256) void qkv_proj(const float* __restrict__ x,
                                                const short* __restrict__ Wt,
                                                short* __restrict__ qb,
                                                short* __restrict__ kb,
                                                short* __restrict__ vb) {
    __shared__ short Xs[64 * SP];
    __shared__ short Ws[192 * SP];
    const int tid  = threadIdx.x;
    const int bm   = blockIdx.x;        // 256 blocks of 64 rows
    const int wv   = tid >> 6;
    const int lane = tid & 63;
    const int l15  = lane & 15, quad = lane >> 4;
    const int mrow = tid >> 2;          // 0..63 staging row
    const int c0   = (tid & 3) << 4;    // 0,16,32,48

    f32x4 acc[12];
#pragma unroll
    for (int i = 0; i < 12; ++i) acc[i] = (f32x4){0.f, 0.f, 0.f, 0.f};

    for (int k0 = 0; k0 < TC; k0 += 64) {
        __syncthreads();
        // stage X tile [64][64] fp32 -> bf16 LDS
        {
            const float4* s = (const float4*)(x + (size_t)(bm * 64 + mrow) * TC + k0 + c0);
            float4 a = s[0], b = s[1], cc = s[2], d = s[3];
            alignas(16) short t16[16];
            t16[0]=f2bf(a.x);  t16[1]=f2bf(a.y);  t16[2]=f2bf(a.z);  t16[3]=f2bf(a.w);
            t16[4]=f2bf(b.x);  t16[5]=f2bf(b.y);  t16[6]=f2bf(b.z);  t16[7]=f2bf(b.w);
            t16[8]=f2bf(cc.x); t16[9]=f2bf(cc.y); t16[10]=f2bf(cc.z);t16[11]=f2bf(cc.w);
            t16[12]=f2bf(d.x); t16[13]=f2bf(d.y); t16[14]=f2bf(d.z); t16[15]=f2bf(d.w);
            *(uint4*)&Xs[mrow * SP + c0]     = *(uint4*)&t16[0];
            *(uint4*)&Xs[mrow * SP + c0 + 8] = *(uint4*)&t16[8];
        }
        // stage W tile [192][64] bf16 (already bf16 in Wt): 768 chunks of 16
#pragma unroll
        for (int i = 0; i < 3; ++i) {
            int ch = tid + i * 256;           // 0..767
            int n  = ch >> 2;
            int cc = (ch & 3) << 4;
            const uint4* s = (const uint4*)(Wt + n * TC + k0 + cc);
            uint4 u0 = s[0], u1 = s[1];
            *(uint4*)&Ws[n * SP + cc]     = u0;
            *(uint4*)&Ws[n * SP + cc + 8] = u1;
        }
        __syncthreads();

        bf16x8 a0 = *(bf16x8*)&Xs[(wv * 16 + l15) * SP + quad * 8];
        bf16x8 a1 = *(bf16x8*)&Xs[(wv * 16 + l15) * SP + quad * 8 + 32];
#pragma unroll
        for (int nt = 0; nt < 12; ++nt) {
            bf16x8 b0 = *(bf16x8*)&Ws[(nt * 16 + l15) * SP + quad * 8];
            bf16x8 b1 = *(bf16x8*)&Ws[(nt * 16 + l15) * SP + quad * 8 + 32];
            acc[nt] = __builtin_amdgcn_mfma_f32_16x16x32_bf16(a0, b0, acc[nt], 0, 0, 0);
            acc[nt] = __builtin_amdgcn_mfma_f32_16x16x32_bf16(a1, b1, acc[nt], 0, 0, 0);
        }
    }
    // epilogue: C-layout row = quad*4+r (+16*wv), col = l15 (+16*nt)
#pragma unroll
    for (int nt = 0; nt < 12; ++nt) {
        int n = nt * 16 + l15;
        short* dst; int d;
        if (n < 64)       { dst = kb; d = n; }
        else if (n < 128) { dst = qb; d = n - 64; }
        else              { dst = vb; d = n - 128; }
#pragma unroll
        for (int r = 0; r < 4; ++r) {
            int m = wv * 16 + quad * 4 + r;
            dst[(size_t)(bm * 64 + m) * TD + d] = f2bf(acc[nt][r]);
        }
    }
}

// ---------------------------------------------------------------------------
// Kernel 3: v[b][t][d] -> vt[b][d][t]  (so PV B-operand reads are contiguous)
// ---------------------------------------------------------------------------
__global__ __launch_bounds__(256) void transpose_v(const short* __restrict__ vb,
                                                   short* __restrict__ vt) {
    __shared__ short Tl[64 * SP];
    const int tid = threadIdx.x;
    const int tc  = blockIdx.x;   // 0..31 (t-chunk)
    const int b   = blockIdx.y;
    const int rr  = tid >> 2;     // 0..63
    const int c0  = (tid & 3) << 4;
    {
        const uint4* s = (const uint4*)(vb + (size_t)(b * TT + tc * 64 + rr) * TD + c0);
        uint4 u0 = s[0], u1 = s[1];
        *(uint4*)&Tl[rr * SP + c0]     = u0;
        *(uint4*)&Tl[rr * SP + c0 + 8] = u1;
    }
    __syncthreads();
    alignas(16) short t16[16];
#pragma unroll
    for (int j = 0; j < 16; ++j) t16[j] = Tl[(c0 + j) * SP + rr];
    uint4* d = (uint4*)(vt + (size_t)(b * TD + rr) * TT + tc * 64 + c0);
    d[0] = *(uint4*)&t16[0];
    d[1] = *(uint4*)&t16[8];
}

// ---------------------------------------------------------------------------
// Kernel 4: flash attention.  One 64-row Q-tile per block, 4 waves, each wave
// owns a 16-row m-slice.  Online softmax in MFMA C-layout; P goes through LDS
// to A-layout for the PV matmul.  Scale d^-0.5 pre-folded into Wq.
// ---------------------------------------------------------------------------
__global__ __launch_bounds__(256) void attn(const short* __restrict__ qb,
                                            const short* __restrict__ kb,
                                            const short* __restrict__ vt,
                                            float* __restrict__ out) {
    __shared__ short Qs[64 * SP];
    __shared__ short Ks[64 * SP];
    __shared__ short Vs[64 * SP];   // [d][s]
    __shared__ short Ps[64 * SP];
    const int tid  = threadIdx.x;
    const int it   = blockIdx.x;    // q tile 0..31
    const int b    = blockIdx.y;
    const int wv   = tid >> 6, lane = tid & 63;
    const int l15  = lane & 15, quad = lane >> 4;
    const int srow = tid >> 2;
    const int c0   = (tid & 3) << 4;
    const float L2E = 1.4426950408889634f;

    // stage Q once
    {
        const uint4* s = (const uint4*)(qb + (size_t)(b * TT + it * 64 + srow) * TD + c0);
        uint4 u0 = s[0], u1 = s[1];
        *(uint4*)&Qs[srow * SP + c0]     = u0;
        *(uint4*)&Qs[srow * SP + c0 + 8] = u1;
    }
    __syncthreads();
    bf16x8 aq0 = *(bf16x8*)&Qs[(wv * 16 + l15) * SP + quad * 8];
    bf16x8 aq1 = *(bf16x8*)&Qs[(wv * 16 + l15) * SP + quad * 8 + 32];

    f32x4 O[4];
#pragma unroll
    for (int i = 0; i < 4; ++i) O[i] = (f32x4){0.f, 0.f, 0.f, 0.f};
    float mrun[4], lrun[4];
#pragma unroll
    for (int r = 0; r < 4; ++r) { mrun[r] = -INFINITY; lrun[r] = 0.f; }

    for (int kt = 0; kt <= it; ++kt) {
        __syncthreads();   // protect Ks/Vs from previous-iteration readers
        {
            const uint4* s = (const uint4*)(kb + (size_t)(b * TT + kt * 64 + srow) * TD + c0);
            uint4 u0 = s[0], u1 = s[1];
            *(uint4*)&Ks[srow * SP + c0]     = u0;
            *(uint4*)&Ks[srow * SP + c0 + 8] = u1;
        }
        {
            const uint4* s = (const uint4*)(vt + (size_t)(b * TD + srow) * TT + kt * 64 + c0);
            uint4 u0 = s[0], u1 = s[1];
            *(uint4*)&Vs[srow * SP + c0]     = u0;
            *(uint4*)&Vs[srow * SP + c0 + 8] = u1;
        }
        __syncthreads();

        // S = Q K^T  (16 rows x 64 cols per wave)
        f32x4 S[4];
#pragma unroll
        for (int nt = 0; nt < 4; ++nt) {
            S[nt] = (f32x4){0.f, 0.f, 0.f, 0.f};
            bf16x8 b0 = *(bf16x8*)&Ks[(nt * 16 + l15) * SP + quad * 8];
            bf16x8 b1 = *(bf16x8*)&Ks[(nt * 16 + l15) * SP + quad * 8 + 32];
            S[nt] = __builtin_amdgcn_mfma_f32_16x16x32_bf16(aq0, b0, S[nt], 0, 0, 0);
            S[nt] = __builtin_amdgcn_mfma_f32_16x16x32_bf16(aq1, b1, S[nt], 0, 0, 0);
        }
        // causal mask on diagonal tile
        if (kt == it) {
#pragma unroll
            for (int nt = 0; nt < 4; ++nt) {
                int scol = nt * 16 + l15;
#pragma unroll
                for (int r = 0; r < 4; ++r) {
                    int qrow = wv * 16 + quad * 4 + r;
                    if (scol > qrow) S[nt][r] = -INFINITY;
                }
            }
        }
        // row max across 64 cols (4 nt regs + 16 lanes of the quad)
        float alpha[4];
#pragma unroll
        for (int r = 0; r < 4; ++r) {
            float v = fmaxf(fmaxf(S[0][r], S[1][r]), fmaxf(S[2][r], S[3][r]));
            v = fmaxf(v, __shfl_xor(v, 1));
            v = fmaxf(v, __shfl_xor(v, 2));
            v = fmaxf(v, __shfl_xor(v, 4));
            v = fmaxf(v, __shfl_xor(v, 8));
            float mnew = fmaxf(mrun[r], v);
            alpha[r] = exp2f((mrun[r] - mnew) * L2E);
            mrun[r] = mnew;
        }
        // p = exp(s - m), row sums, spill P (own wave's rows -> no barrier)
        float ps[4] = {0.f, 0.f, 0.f, 0.f};
#pragma unroll
        for (int nt = 0; nt < 4; ++nt) {
#pragma unroll
            for (int r = 0; r < 4; ++r) {
                float p = exp2f((S[nt][r] - mrun[r]) * L2E);
                ps[r] += p;
                Ps[(wv * 16 + quad * 4 + r) * SP + nt * 16 + l15] = f2bf(p);
            }
        }
#pragma unroll
        for (int r = 0; r < 4; ++r) {
            float v = ps[r];
            v += __shfl_xor(v, 1);
            v += __shfl_xor(v, 2);
            v += __shfl_xor(v, 4);
            v += __shfl_xor(v, 8);
            lrun[r] = alpha[r] * lrun[r] + v;
        }
#pragma unroll
        for (int i = 0; i < 4; ++i)
#pragma unroll
            for (int r = 0; r < 4; ++r) O[i][r] *= alpha[r];

        // O += P V   (A = P rows of this wave, B = Vs = V^T)
        bf16x8 p0 = *(bf16x8*)&Ps[(wv * 16 + l15) * SP + quad * 8];
        bf16x8 p1 = *(bf16x8*)&Ps[(wv * 16 + l15) * SP + quad * 8 + 32];
#pragma unroll
        for (int dt = 0; dt < 4; ++dt) {
            bf16x8 b0 = *(bf16x8*)&Vs[(dt * 16 + l15) * SP + quad * 8];
            bf16x8 b1 = *(bf16x8*)&Vs[(dt * 16 + l15) * SP + quad * 8 + 32];
            O[dt] = __builtin_amdgcn_mfma_f32_16x16x32_bf16(p0, b0, O[dt], 0, 0, 0);
            O[dt] = __builtin_amdgcn_mfma_f32_16x16x32_bf16(p1, b1, O[dt], 0, 0, 0);
        }
    }
    // epilogue: out[b][t][d] = O / l   (fp32)
#pragma unroll
    for (int dt = 0; dt < 4; ++dt) {
#pragma unroll
        for (int r = 0; r < 4; ++r) {
            int m = wv * 16 + quad * 4 + r;
            out[(size_t)(b * TT + it * 64 + m) * TD + dt * 16 + l15] = O[dt][r] / lrun[r];
        }
    }
}

// ---------------------------------------------------------------------------
extern "C" void kernel_launch(void* const* d_in, const int* in_sizes, int n_in,
                              void* d_out, int out_size, void* d_ws, size_t ws_size,
                              hipStream_t stream) {
    const float* x  = (const float*)d_in[0];
    const float* Wk = (const float*)d_in[1];
    const float* Wq = (const float*)d_in[2];
    const float* Wv = (const float*)d_in[3];
    float* out = (float*)d_out;

    char* ws = (char*)d_ws;
    // layout: Wt bf16 [192][1024] | qb | kb | vb | vt  (each 16384*64 bf16 = 2MB)
    short* Wt = (short*)(ws);
    short* qb = (short*)(ws + 524288);
    short* kb = (short*)(ws + 2621440);
    short* vb = (short*)(ws + 4718592);
    short* vt = (short*)(ws + 6815744);

    convert_w<<<dim3(192), dim3(256), 0, stream>>>(Wk, Wq, Wv, Wt);
    qkv_proj<<<dim3(256), dim3(256), 0, stream>>>(x, Wt, qb, kb, vb);
    transpose_v<<<dim3(32, 8), dim3(256), 0, stream>>>(vb, vt);
    attn<<<dim3(32, 8), dim3(256), 0, stream>>>(qb, kb, vt, out);
}